// Round 1
// baseline (1221.556 us; speedup 1.0000x reference)
//
#include <hip/hip_runtime.h>
#include <type_traits>

// Problem dims
#define TDIM 4
#define BDIM 8
#define CDIM 512
#define NDIM 1024
#define HDIM 8
#define DDIM 64
#define BCN  (BDIM*CDIM*NDIM)      // 4194304
#define TBCN (TDIM*BCN)            // 16777216

// ---------------------------------------------------------------------------
// GEMM: Y[batch, o, n] = sum_c W[o,c] * X[batch, c, n]  (+ bias[o] if given)
// batch = t*B+b (32), W: 512x512 f32, X: 512x1024 (f32 or u8 spikes)
// 64x64 output tile per block, 256 threads, 4x4 per thread, K-tile 16.
// ---------------------------------------------------------------------------
template <typename XT>
__global__ __launch_bounds__(256) void conv_gemm(
    const float* __restrict__ W, const XT* __restrict__ X,
    float* __restrict__ Y, const float* __restrict__ bias)
{
    const int batch = blockIdx.z;
    const XT* Xb = X + (size_t)batch * CDIM * NDIM;
    float*    Yb = Y + (size_t)batch * CDIM * NDIM;
    const int o0 = blockIdx.y * 64;
    const int n0 = blockIdx.x * 64;

    __shared__ float sW[16][64];   // [k][o]
    __shared__ float sX[16][64];   // [k][n]

    const int tid = threadIdx.x;
    const int tx = tid & 15, ty = tid >> 4;
    const int woo = tid >> 2, wcq = tid & 3;   // W load: row o0+woo, 4 k's
    const int xk = tid >> 4, xn = (tid & 15) * 4;

    float acc[4][4] = {};

    for (int k0 = 0; k0 < CDIM; k0 += 16) {
        float4 wv = *(const float4*)(W + (size_t)(o0 + woo) * CDIM + k0 + wcq * 4);
        float4 xv;
        if constexpr (std::is_same<XT, float>::value) {
            xv = *(const float4*)(Xb + (size_t)(k0 + xk) * NDIM + n0 + xn);
        } else {
            uchar4 u = *(const uchar4*)(Xb + (size_t)(k0 + xk) * NDIM + n0 + xn);
            xv = make_float4((float)u.x, (float)u.y, (float)u.z, (float)u.w);
        }
        __syncthreads();           // previous iteration's reads done
        sW[wcq * 4 + 0][woo] = wv.x;
        sW[wcq * 4 + 1][woo] = wv.y;
        sW[wcq * 4 + 2][woo] = wv.z;
        sW[wcq * 4 + 3][woo] = wv.w;
        *(float4*)&sX[xk][xn] = xv;
        __syncthreads();

        #pragma unroll
        for (int kk = 0; kk < 16; ++kk) {
            float4 a4 = *(float4*)&sW[kk][ty * 4];
            float4 b4 = *(float4*)&sX[kk][tx * 4];
            float a_[4] = {a4.x, a4.y, a4.z, a4.w};
            float b_[4] = {b4.x, b4.y, b4.z, b4.w};
            #pragma unroll
            for (int i = 0; i < 4; ++i)
                #pragma unroll
                for (int j = 0; j < 4; ++j)
                    acc[i][j] += a_[i] * b_[j];
        }
    }

    #pragma unroll
    for (int i = 0; i < 4; ++i) {
        const int o = o0 + ty * 4 + i;
        const float bv = bias ? bias[o] : 0.0f;
        float4 r = make_float4(acc[i][0] + bv, acc[i][1] + bv,
                               acc[i][2] + bv, acc[i][3] + bv);
        *(float4*)(Yb + (size_t)o * NDIM + n0 + tx * 4) = r;
    }
}

// ---------------------------------------------------------------------------
// BN (optional) + LIF over T. One thread per (b,c,n); loops t sequentially.
// OUT_MODE 0: u8 spikes (+ optional ballot-packed bits along n), 1: f32 out.
// v = v + (x - v)/2 ; s = (v >= vth) ; v *= (1-s)
// ---------------------------------------------------------------------------
template <int OUT_MODE>
__global__ __launch_bounds__(256) void lif_bn(
    const float* __restrict__ Y,
    const float* __restrict__ g, const float* __restrict__ b,
    const float* __restrict__ m, const float* __restrict__ var,
    float vth,
    unsigned char* __restrict__ s8, float* __restrict__ sf,
    unsigned long long* __restrict__ bits)
{
    const int idx = blockIdx.x * 256 + threadIdx.x;   // over B*C*N
    const int c = (idx >> 10) & (CDIM - 1);           // idx / N % C
    float inv = 1.0f, beta = 0.0f;
    if (g) {
        const float iv = g[c] / sqrtf(var[c] + 1e-5f);
        inv = iv;
        beta = __fsub_rn(b[c], __fmul_rn(m[c], iv));
    }
    float v = 0.0f;
    #pragma unroll
    for (int t = 0; t < TDIM; ++t) {
        float x = Y[(size_t)t * BCN + idx];
        x = __fadd_rn(__fmul_rn(x, inv), beta);       // match jax mul-then-add
        v = __fadd_rn(v, __fmul_rn(__fsub_rn(x, v), 0.5f));
        const float s = (v >= vth) ? 1.0f : 0.0f;
        v = v * (1.0f - s);
        if (OUT_MODE == 0) s8[(size_t)t * BCN + idx] = (unsigned char)s;
        else               sf[(size_t)t * BCN + idx] = s;
        if (bits) {
            unsigned long long mask = __ballot(s != 0.0f);
            if ((threadIdx.x & 63) == 0)
                bits[((size_t)t * BCN + idx) >> 6] = mask;
        }
    }
}

// ---------------------------------------------------------------------------
// v-branch spikes -> heads layout: out[t,b,h,n,dd] = sv[t,b,h*64+dd,n] (f32)
// grid: (N/64, T*B*H); 64x64 transpose tile per block.
// ---------------------------------------------------------------------------
__global__ __launch_bounds__(256) void v_transpose(
    const unsigned char* __restrict__ sv, float* __restrict__ out)
{
    const int tbh = blockIdx.y;        // (t*B+b)*H + h
    const int h = tbh & 7, tb = tbh >> 3;
    const int n0 = blockIdx.x * 64;
    __shared__ unsigned char tile[64][65];   // [dd][n]
    const int tid = threadIdx.x;
    const int lane = tid & 63;
    for (int dd = tid >> 6; dd < 64; dd += 4)
        tile[dd][lane] = sv[((size_t)tb * CDIM + h * 64 + dd) * NDIM + n0 + lane];
    __syncthreads();
    for (int nn = tid >> 6; nn < 64; nn += 4)
        out[((size_t)tbh * NDIM + n0 + nn) * 64 + lane] = (float)tile[lane][nn];
}

// ---------------------------------------------------------------------------
// kv[tbh,dd,e] = sum_n k[dd,n]*v[e,n]  via popcount(AND) on bitpacked spikes.
// one block per (t,b,h); bits: row c has N/64=16 u64 words.
// ---------------------------------------------------------------------------
__global__ __launch_bounds__(256) void kv_gemm(
    const unsigned long long* __restrict__ kb,
    const unsigned long long* __restrict__ vb,
    float* __restrict__ kv)
{
    const int tbh = blockIdx.x;
    const int h = tbh & 7, tb = tbh >> 3;
    __shared__ unsigned long long sk[64][16], sv[64][16];
    const int tid = threadIdx.x;
    for (int i = tid; i < 1024; i += 256) {
        const int dd = i >> 4, w = i & 15;
        const size_t row = ((size_t)tb * CDIM + h * 64 + dd) * 16 + w;
        sk[dd][w] = kb[row];
        sv[dd][w] = vb[row];
    }
    __syncthreads();
    const int dd = tid >> 2, e0 = (tid & 3) * 16;
    #pragma unroll
    for (int j = 0; j < 16; ++j) {
        int acc = 0;
        #pragma unroll
        for (int w = 0; w < 16; ++w)
            acc += __popcll(sk[dd][w] & sv[e0 + j][w]);
        kv[((size_t)tbh * 64 + dd) * 64 + e0 + j] = (float)acc;
    }
}

// ---------------------------------------------------------------------------
// a[t,b,h*64+e,n] = 0.125 * sum_dd sq[t,b,h*64+dd,n] * kv[tbh,dd,e]
// grid: (N/64, T*B*H); 64(e)x64(n) tile, K=64. Exact small-int arithmetic.
// ---------------------------------------------------------------------------
__global__ __launch_bounds__(256) void a_gemm(
    const float* __restrict__ kv, const unsigned char* __restrict__ sq,
    float* __restrict__ Y)
{
    const int tbh = blockIdx.y;
    const int h = tbh & 7, tb = tbh >> 3;
    const int n0 = blockIdx.x * 64;
    __shared__ float skv[64][65];    // [dd][e]
    __shared__ float sqt[64][64];    // [dd][n]
    const int tid = threadIdx.x;
    for (int i = tid; i < 4096; i += 256)
        skv[i >> 6][i & 63] = kv[(size_t)tbh * 4096 + i];
    const int lane = tid & 63;
    for (int dd = tid >> 6; dd < 64; dd += 4)
        sqt[dd][lane] = (float)sq[((size_t)tb * CDIM + h * 64 + dd) * NDIM + n0 + lane];
    __syncthreads();

    const int tx = tid & 15, ty = tid >> 4;   // e = ty*4.., n = n0+tx*4..
    float acc[4][4] = {};
    #pragma unroll 8
    for (int dd = 0; dd < 64; ++dd) {
        float a_[4];
        #pragma unroll
        for (int i = 0; i < 4; ++i) a_[i] = skv[dd][ty * 4 + i];
        float4 b4 = *(float4*)&sqt[dd][tx * 4];
        float b_[4] = {b4.x, b4.y, b4.z, b4.w};
        #pragma unroll
        for (int i = 0; i < 4; ++i)
            #pragma unroll
            for (int j = 0; j < 4; ++j)
                acc[i][j] += a_[i] * b_[j];
    }
    #pragma unroll
    for (int i = 0; i < 4; ++i) {
        const int e = ty * 4 + i;
        float4 r = make_float4(acc[i][0] * 0.125f, acc[i][1] * 0.125f,
                               acc[i][2] * 0.125f, acc[i][3] * 0.125f);
        *(float4*)(Y + ((size_t)tb * CDIM + h * 64 + e) * NDIM + n0 + tx * 4) = r;
    }
}

// ---------------------------------------------------------------------------
extern "C" void kernel_launch(void* const* d_in, const int* in_sizes, int n_in,
                              void* d_out, int out_size, void* d_ws, size_t ws_size,
                              hipStream_t stream)
{
    const float* x  = (const float*)d_in[0];
    const float* wq = (const float*)d_in[2];
    const float* gq = (const float*)d_in[3];
    const float* bq = (const float*)d_in[4];
    const float* mq = (const float*)d_in[5];
    const float* vq = (const float*)d_in[6];
    const float* wk = (const float*)d_in[7];
    const float* gk = (const float*)d_in[8];
    const float* bk = (const float*)d_in[9];
    const float* mk = (const float*)d_in[10];
    const float* vk = (const float*)d_in[11];
    const float* wv = (const float*)d_in[12];
    const float* gv = (const float*)d_in[13];
    const float* bv = (const float*)d_in[14];
    const float* mv = (const float*)d_in[15];
    const float* vv = (const float*)d_in[16];
    const float* wp = (const float*)d_in[17];
    const float* pb = (const float*)d_in[18];
    const float* gp = (const float*)d_in[19];
    const float* bp = (const float*)d_in[20];
    const float* mp = (const float*)d_in[21];
    const float* vp = (const float*)d_in[22];
    (void)in_sizes; (void)n_in; (void)out_size; (void)ws_size;

    // workspace carve (needs ~136 MB)
    char* w = (char*)d_ws;
    float* Y = (float*)w;                    w += (size_t)TBCN * 4;  // 64 MB
    unsigned char* sq = (unsigned char*)w;   w += TBCN;              // 16 MB
    unsigned char* sk = (unsigned char*)w;   w += TBCN;
    unsigned char* sv = (unsigned char*)w;   w += TBCN;
    unsigned char* sa = (unsigned char*)w;   w += TBCN;
    unsigned long long* kb = (unsigned long long*)w; w += TBCN / 8;  // 2 MB
    unsigned long long* vb = (unsigned long long*)w; w += TBCN / 8;
    float* kvbuf = (float*)w;                w += (size_t)256 * 64 * 64 * 4; // 4 MB

    float* out_spk = (float*)d_out;          // (T,B,C,N)
    float* out_v   = (float*)d_out + TBCN;   // (T,B,H,N,d)

    const dim3 blk(256);
    const dim3 gemmGrid(NDIM / 64, CDIM / 64, TDIM * BDIM);  // 16,8,32
    const int lifGrid = BCN / 256;                           // 16384

    // q branch
    conv_gemm<float><<<gemmGrid, blk, 0, stream>>>(wq, x, Y, nullptr);
    lif_bn<0><<<lifGrid, blk, 0, stream>>>(Y, gq, bq, mq, vq, 1.0f, sq, nullptr, nullptr);
    // k branch (also bitpack)
    conv_gemm<float><<<gemmGrid, blk, 0, stream>>>(wk, x, Y, nullptr);
    lif_bn<0><<<lifGrid, blk, 0, stream>>>(Y, gk, bk, mk, vk, 1.0f, sk, nullptr, kb);
    // v branch (also bitpack)
    conv_gemm<float><<<gemmGrid, blk, 0, stream>>>(wv, x, Y, nullptr);
    lif_bn<0><<<lifGrid, blk, 0, stream>>>(Y, gv, bv, mv, vv, 1.0f, sv, nullptr, vb);
    // v spikes -> heads layout output
    v_transpose<<<dim3(NDIM / 64, TDIM * BDIM * HDIM), blk, 0, stream>>>(sv, out_v);
    // attention (exact integer arithmetic)
    kv_gemm<<<TDIM * BDIM * HDIM, blk, 0, stream>>>(kb, vb, kvbuf);
    a_gemm<<<dim3(NDIM / 64, TDIM * BDIM * HDIM), blk, 0, stream>>>(kvbuf, sq, Y);
    lif_bn<0><<<lifGrid, blk, 0, stream>>>(Y, nullptr, nullptr, nullptr, nullptr, 0.5f, sa, nullptr, nullptr);
    // projection conv on binary spikes + bias, then BN + LIF -> out
    conv_gemm<unsigned char><<<gemmGrid, blk, 0, stream>>>(wp, sa, Y, pb);
    lif_bn<1><<<lifGrid, blk, 0, stream>>>(Y, gp, bp, mp, vp, 1.0f, nullptr, out_spk, nullptr);
}

// Round 5
// 1090.164 us; speedup vs baseline: 1.1205x; 1.1205x over previous
//
#include <hip/hip_runtime.h>
#include <type_traits>

// Problem dims
#define TDIM 4
#define BDIM 8
#define CDIM 512
#define NDIM 1024
#define HDIM 8
#define DDIM 64
#define BCN  (BDIM*CDIM*NDIM)      // 4194304
#define TBCN (TDIM*BCN)            // 16777216

// ---------------------------------------------------------------------------
// GEMM: Y[batch, o, n] = sum_c W[o,c] * X[batch, c, n]  (+ bias[o] if given)
// 256(o) x 128(n) tile per block, 256 threads, 16x8 per thread, K-tile 16.
// LDS traffic: 6 x ds_read_b128 per 256 FLOP = 0.375 B/FLOP (was 1.0).
// Accumulation is k-sequential per output -> bit-identical to round-1 kernel.
// ---------------------------------------------------------------------------
template <typename XT>
__global__ __launch_bounds__(256, 2) void conv_gemm(
    const float* __restrict__ W, const XT* __restrict__ X,
    float* __restrict__ Y, const float* __restrict__ bias)
{
    const int batch = blockIdx.z;
    const XT* Xb = X + (size_t)batch * CDIM * NDIM;
    float*    Yb = Y + (size_t)batch * CDIM * NDIM;
    const int o0 = blockIdx.y * 256;
    const int n0 = blockIdx.x * 128;

    __shared__ float sW[16][256];   // [k][o]
    __shared__ float sX[16][128];   // [k][n]

    const int tid = threadIdx.x;
    const int tx = tid & 15, ty = tid >> 4;      // col-thread, row-thread
    const int xk = tid >> 4, xn = (tid & 15) * 8;

    float acc[16][8] = {};

    for (int k0 = 0; k0 < CDIM; k0 += 16) {
        // --- stage W: each thread owns one o-row (o0+tid), 16 k's ---
        float4 w0 = *(const float4*)(W + (size_t)(o0 + tid) * CDIM + k0 + 0);
        float4 w1 = *(const float4*)(W + (size_t)(o0 + tid) * CDIM + k0 + 4);
        float4 w2 = *(const float4*)(W + (size_t)(o0 + tid) * CDIM + k0 + 8);
        float4 w3 = *(const float4*)(W + (size_t)(o0 + tid) * CDIM + k0 + 12);
        // --- stage X: 8 elems at row xk, cols n0+xn.. ---
        float xb[8];
        if constexpr (std::is_same<XT, float>::value) {
            float4 x0 = *(const float4*)(Xb + (size_t)(k0 + xk) * NDIM + n0 + xn);
            float4 x1 = *(const float4*)(Xb + (size_t)(k0 + xk) * NDIM + n0 + xn + 4);
            xb[0]=x0.x; xb[1]=x0.y; xb[2]=x0.z; xb[3]=x0.w;
            xb[4]=x1.x; xb[5]=x1.y; xb[6]=x1.z; xb[7]=x1.w;
        } else {
            uchar4 u0 = *(const uchar4*)(Xb + (size_t)(k0 + xk) * NDIM + n0 + xn);
            uchar4 u1 = *(const uchar4*)(Xb + (size_t)(k0 + xk) * NDIM + n0 + xn + 4);
            xb[0]=(float)u0.x; xb[1]=(float)u0.y; xb[2]=(float)u0.z; xb[3]=(float)u0.w;
            xb[4]=(float)u1.x; xb[5]=(float)u1.y; xb[6]=(float)u1.z; xb[7]=(float)u1.w;
        }
        __syncthreads();           // previous iteration's LDS reads done
        sW[ 0][tid] = w0.x; sW[ 1][tid] = w0.y; sW[ 2][tid] = w0.z; sW[ 3][tid] = w0.w;
        sW[ 4][tid] = w1.x; sW[ 5][tid] = w1.y; sW[ 6][tid] = w1.z; sW[ 7][tid] = w1.w;
        sW[ 8][tid] = w2.x; sW[ 9][tid] = w2.y; sW[10][tid] = w2.z; sW[11][tid] = w2.w;
        sW[12][tid] = w3.x; sW[13][tid] = w3.y; sW[14][tid] = w3.z; sW[15][tid] = w3.w;
        #pragma unroll
        for (int j = 0; j < 8; ++j) sX[xk][xn + j] = xb[j];
        __syncthreads();

        #pragma unroll
        for (int kk = 0; kk < 16; ++kk) {
            // rows: p*64 + ty*4 + i (p<4) ; cols: q*64 + tx*4 + j (q<2)
            float4 a0 = *(float4*)&sW[kk][  0 + ty * 4];
            float4 a1 = *(float4*)&sW[kk][ 64 + ty * 4];
            float4 a2 = *(float4*)&sW[kk][128 + ty * 4];
            float4 a3 = *(float4*)&sW[kk][192 + ty * 4];
            float4 b0 = *(float4*)&sX[kk][  0 + tx * 4];
            float4 b1 = *(float4*)&sX[kk][ 64 + tx * 4];
            float ar[16] = {a0.x,a0.y,a0.z,a0.w, a1.x,a1.y,a1.z,a1.w,
                            a2.x,a2.y,a2.z,a2.w, a3.x,a3.y,a3.z,a3.w};
            float br[8]  = {b0.x,b0.y,b0.z,b0.w, b1.x,b1.y,b1.z,b1.w};
            #pragma unroll
            for (int i = 0; i < 16; ++i)
                #pragma unroll
                for (int j = 0; j < 8; ++j)
                    acc[i][j] += ar[i] * br[j];
        }
    }

    #pragma unroll
    for (int p = 0; p < 4; ++p) {
        #pragma unroll
        for (int i = 0; i < 4; ++i) {
            const int o = o0 + p * 64 + ty * 4 + i;
            const float bv = bias ? bias[o] : 0.0f;
            float* rowp = Yb + (size_t)o * NDIM + n0;
            const int ai = p * 4 + i;
            float4 r0 = make_float4(acc[ai][0] + bv, acc[ai][1] + bv,
                                    acc[ai][2] + bv, acc[ai][3] + bv);
            float4 r1 = make_float4(acc[ai][4] + bv, acc[ai][5] + bv,
                                    acc[ai][6] + bv, acc[ai][7] + bv);
            *(float4*)(rowp + tx * 4) = r0;
            *(float4*)(rowp + 64 + tx * 4) = r1;
        }
    }
}

// ---------------------------------------------------------------------------
// BN (optional) + LIF over T. One thread per (b,c,n); loops t sequentially.
// OUT_MODE 0: u8 spikes (+ optional ballot-packed bits along n), 1: f32 out.
// ---------------------------------------------------------------------------
template <int OUT_MODE>
__global__ __launch_bounds__(256) void lif_bn(
    const float* __restrict__ Y,
    const float* __restrict__ g, const float* __restrict__ b,
    const float* __restrict__ m, const float* __restrict__ var,
    float vth,
    unsigned char* __restrict__ s8, float* __restrict__ sf,
    unsigned long long* __restrict__ bits)
{
    const int idx = blockIdx.x * 256 + threadIdx.x;   // over B*C*N
    const int c = (idx >> 10) & (CDIM - 1);
    float inv = 1.0f, beta = 0.0f;
    if (g) {
        const float iv = g[c] / sqrtf(var[c] + 1e-5f);
        inv = iv;
        beta = __fsub_rn(b[c], __fmul_rn(m[c], iv));
    }
    float v = 0.0f;
    #pragma unroll
    for (int t = 0; t < TDIM; ++t) {
        float x = Y[(size_t)t * BCN + idx];
        x = __fadd_rn(__fmul_rn(x, inv), beta);
        v = __fadd_rn(v, __fmul_rn(__fsub_rn(x, v), 0.5f));
        const float s = (v >= vth) ? 1.0f : 0.0f;
        v = v * (1.0f - s);
        if (OUT_MODE == 0) s8[(size_t)t * BCN + idx] = (unsigned char)s;
        else               sf[(size_t)t * BCN + idx] = s;
        if (bits) {
            unsigned long long mask = __ballot(s != 0.0f);
            if ((threadIdx.x & 63) == 0)
                bits[((size_t)t * BCN + idx) >> 6] = mask;
        }
    }
}

// ---------------------------------------------------------------------------
// v-branch spikes -> heads layout: out[t,b,h,n,dd] = sv[t,b,h*64+dd,n] (f32)
// ---------------------------------------------------------------------------
__global__ __launch_bounds__(256) void v_transpose(
    const unsigned char* __restrict__ sv, float* __restrict__ out)
{
    const int tbh = blockIdx.y;
    const int h = tbh & 7, tb = tbh >> 3;
    const int n0 = blockIdx.x * 64;
    __shared__ unsigned char tile[64][65];
    const int tid = threadIdx.x;
    const int lane = tid & 63;
    for (int dd = tid >> 6; dd < 64; dd += 4)
        tile[dd][lane] = sv[((size_t)tb * CDIM + h * 64 + dd) * NDIM + n0 + lane];
    __syncthreads();
    for (int nn = tid >> 6; nn < 64; nn += 4)
        out[((size_t)tbh * NDIM + n0 + nn) * 64 + lane] = (float)tile[lane][nn];
}

// ---------------------------------------------------------------------------
// kv[tbh,dd,e] = sum_n k[dd,n]*v[e,n] via popcount(AND) on bitpacked spikes.
// ---------------------------------------------------------------------------
__global__ __launch_bounds__(256) void kv_gemm(
    const unsigned long long* __restrict__ kb,
    const unsigned long long* __restrict__ vb,
    float* __restrict__ kv)
{
    const int tbh = blockIdx.x;
    const int h = tbh & 7, tb = tbh >> 3;
    __shared__ unsigned long long sk[64][16], sv[64][16];
    const int tid = threadIdx.x;
    for (int i = tid; i < 1024; i += 256) {
        const int dd = i >> 4, w = i & 15;
        const size_t row = ((size_t)tb * CDIM + h * 64 + dd) * 16 + w;
        sk[dd][w] = kb[row];
        sv[dd][w] = vb[row];
    }
    __syncthreads();
    const int dd = tid >> 2, e0 = (tid & 3) * 16;
    #pragma unroll
    for (int j = 0; j < 16; ++j) {
        int acc = 0;
        #pragma unroll
        for (int w = 0; w < 16; ++w)
            acc += __popcll(sk[dd][w] & sv[e0 + j][w]);
        kv[((size_t)tbh * 64 + dd) * 64 + e0 + j] = (float)acc;
    }
}

// ---------------------------------------------------------------------------
// a[t,b,h*64+e,n] = 0.125 * sum_dd sq[t,b,h*64+dd,n] * kv[tbh,dd,e]
// ---------------------------------------------------------------------------
__global__ __launch_bounds__(256) void a_gemm(
    const float* __restrict__ kv, const unsigned char* __restrict__ sq,
    float* __restrict__ Y)
{
    const int tbh = blockIdx.y;
    const int h = tbh & 7, tb = tbh >> 3;
    const int n0 = blockIdx.x * 64;
    __shared__ float skv[64][65];    // [dd][e]
    __shared__ float sqt[64][64];    // [dd][n]
    const int tid = threadIdx.x;
    for (int i = tid; i < 4096; i += 256)
        skv[i >> 6][i & 63] = kv[(size_t)tbh * 4096 + i];
    const int lane = tid & 63;
    for (int dd = tid >> 6; dd < 64; dd += 4)
        sqt[dd][lane] = (float)sq[((size_t)tb * CDIM + h * 64 + dd) * NDIM + n0 + lane];
    __syncthreads();

    const int tx = tid & 15, ty = tid >> 4;
    float acc[4][4] = {};
    #pragma unroll 8
    for (int dd = 0; dd < 64; ++dd) {
        float a_[4];
        #pragma unroll
        for (int i = 0; i < 4; ++i) a_[i] = skv[dd][ty * 4 + i];
        float4 b4 = *(float4*)&sqt[dd][tx * 4];
        float b_[4] = {b4.x, b4.y, b4.z, b4.w};
        #pragma unroll
        for (int i = 0; i < 4; ++i)
            #pragma unroll
            for (int j = 0; j < 4; ++j)
                acc[i][j] += a_[i] * b_[j];
    }
    #pragma unroll
    for (int i = 0; i < 4; ++i) {
        const int e = ty * 4 + i;
        float4 r = make_float4(acc[i][0] * 0.125f, acc[i][1] * 0.125f,
                               acc[i][2] * 0.125f, acc[i][3] * 0.125f);
        *(float4*)(Y + ((size_t)tb * CDIM + h * 64 + e) * NDIM + n0 + tx * 4) = r;
    }
}

// ---------------------------------------------------------------------------
extern "C" void kernel_launch(void* const* d_in, const int* in_sizes, int n_in,
                              void* d_out, int out_size, void* d_ws, size_t ws_size,
                              hipStream_t stream)
{
    const float* x  = (const float*)d_in[0];
    const float* wq = (const float*)d_in[2];
    const float* gq = (const float*)d_in[3];
    const float* bq = (const float*)d_in[4];
    const float* mq = (const float*)d_in[5];
    const float* vq = (const float*)d_in[6];
    const float* wk = (const float*)d_in[7];
    const float* gk = (const float*)d_in[8];
    const float* bk = (const float*)d_in[9];
    const float* mk = (const float*)d_in[10];
    const float* vk = (const float*)d_in[11];
    const float* wv = (const float*)d_in[12];
    const float* gv = (const float*)d_in[13];
    const float* bv = (const float*)d_in[14];
    const float* mv = (const float*)d_in[15];
    const float* vv = (const float*)d_in[16];
    const float* wp = (const float*)d_in[17];
    const float* pb = (const float*)d_in[18];
    const float* gp = (const float*)d_in[19];
    const float* bp = (const float*)d_in[20];
    const float* mp = (const float*)d_in[21];
    const float* vp = (const float*)d_in[22];
    (void)in_sizes; (void)n_in; (void)out_size; (void)ws_size;

    // workspace carve (~136 MB, same as round 1)
    char* w = (char*)d_ws;
    float* Y = (float*)w;                    w += (size_t)TBCN * 4;  // 64 MB
    unsigned char* sq = (unsigned char*)w;   w += TBCN;              // 16 MB
    unsigned char* sk = (unsigned char*)w;   w += TBCN;
    unsigned char* sv = (unsigned char*)w;   w += TBCN;
    unsigned char* sa = (unsigned char*)w;   w += TBCN;
    unsigned long long* kb = (unsigned long long*)w; w += TBCN / 8;  // 2 MB
    unsigned long long* vb = (unsigned long long*)w; w += TBCN / 8;
    float* kvbuf = (float*)w;                w += (size_t)256 * 64 * 64 * 4; // 4 MB

    float* out_spk = (float*)d_out;          // (T,B,C,N)
    float* out_v   = (float*)d_out + TBCN;   // (T,B,H,N,d)

    const dim3 blk(256);
    const dim3 gemmGrid(NDIM / 128, CDIM / 256, TDIM * BDIM);  // 8,2,32 = 512 blocks
    const int lifGrid = BCN / 256;                             // 16384

    // q branch
    conv_gemm<float><<<gemmGrid, blk, 0, stream>>>(wq, x, Y, nullptr);
    lif_bn<0><<<lifGrid, blk, 0, stream>>>(Y, gq, bq, mq, vq, 1.0f, sq, nullptr, nullptr);
    // k branch (also bitpack)
    conv_gemm<float><<<gemmGrid, blk, 0, stream>>>(wk, x, Y, nullptr);
    lif_bn<0><<<lifGrid, blk, 0, stream>>>(Y, gk, bk, mk, vk, 1.0f, sk, nullptr, kb);
    // v branch (also bitpack)
    conv_gemm<float><<<gemmGrid, blk, 0, stream>>>(wv, x, Y, nullptr);
    lif_bn<0><<<lifGrid, blk, 0, stream>>>(Y, gv, bv, mv, vv, 1.0f, sv, nullptr, vb);
    // v spikes -> heads layout output
    v_transpose<<<dim3(NDIM / 64, TDIM * BDIM * HDIM), blk, 0, stream>>>(sv, out_v);
    // attention (exact integer arithmetic)
    kv_gemm<<<TDIM * BDIM * HDIM, blk, 0, stream>>>(kb, vb, kvbuf);
    a_gemm<<<dim3(NDIM / 64, TDIM * BDIM * HDIM), blk, 0, stream>>>(kvbuf, sq, Y);
    lif_bn<0><<<lifGrid, blk, 0, stream>>>(Y, nullptr, nullptr, nullptr, nullptr, 0.5f, sa, nullptr, nullptr);
    // projection conv on binary spikes + bias, then BN + LIF -> out
    conv_gemm<unsigned char><<<gemmGrid, blk, 0, stream>>>(wp, sa, Y, pb);
    lif_bn<1><<<lifGrid, blk, 0, stream>>>(Y, gp, bp, mp, vp, 1.0f, nullptr, out_spk, nullptr);
}

// Round 6
// 780.900 us; speedup vs baseline: 1.5643x; 1.3960x over previous
//
#include <hip/hip_runtime.h>

// Problem dims
#define TDIM 4
#define BDIM 8
#define CDIM 512
#define NDIM 1024
#define HDIM 8
#define DDIM 64
#define BCN  (BDIM*CDIM*NDIM)      // 4194304
#define TBCN ((size_t)TDIM*BCN)    // 16777216
#define WFRS 262144                // 512*512 elements per weight split

typedef __attribute__((ext_vector_type(8))) short bf16x8;
typedef __attribute__((ext_vector_type(4))) float f32x4;
typedef unsigned long long u64;
typedef unsigned short ushort_t;

// round-to-nearest-even f32 -> bf16 (as ushort)
__device__ __forceinline__ unsigned short f2bf(float f) {
    unsigned int u = __float_as_uint(f);
    u = (u + 0x7FFFu + ((u >> 16) & 1u)) >> 16;
    return (unsigned short)u;
}
__device__ __forceinline__ float bf2f(unsigned short h) {
    return __uint_as_float(((unsigned int)h) << 16);
}

// ---------------------------------------------------------------------------
// Weight split: W (512x512 f32) -> 3 bf16 splits in MFMA A-fragment order.
// A-frag layout (per split): [ob(32)][kb(16)][lane(64)][i(8)],
//   lane = (o&15) | (((c>>3)&3)<<4), i = c&7  (o row, c = k).
// ---------------------------------------------------------------------------
__global__ __launch_bounds__(256) void wsplit(
    const float* __restrict__ W, unsigned short* __restrict__ Wfr)
{
    const int idx = blockIdx.x * 256 + threadIdx.x;   // o*512 + c
    const int o = idx >> 9, c = idx & 511;
    const float v = W[idx];
    const unsigned short h1 = f2bf(v);
    const float r1 = v - bf2f(h1);
    const unsigned short h2 = f2bf(r1);
    const float r2 = r1 - bf2f(h2);
    const unsigned short h3 = f2bf(r2);
    const size_t fo = ((((size_t)(o >> 4)) * 16 + (c >> 5)) * 64 +
                       ((o & 15) | (((c >> 3) & 3) << 4))) * 8 + (c & 7);
    Wfr[fo]             = h1;
    Wfr[WFRS + fo]      = h2;
    Wfr[2 * WFRS + fo]  = h3;
}

// ---------------------------------------------------------------------------
// x split: x (T*B,512,1024 f32) -> 3 bf16 splits in MFMA B-fragment order.
// B-frag layout (per split): [tb(32)][nb(64)][kb(16)][lane(64)][i(8)],
//   lane = (n&15) | (((c>>3)&3)<<4), i = c&7  (c = k, n col).
// ---------------------------------------------------------------------------
__global__ __launch_bounds__(256) void xsplit(
    const float* __restrict__ X, unsigned short* __restrict__ xfr)
{
    const size_t idx = (size_t)blockIdx.x * 256 + threadIdx.x;  // over TBCN
    const int n = (int)(idx & 1023);
    const int c = (int)(idx >> 10) & 511;
    const int tb = (int)(idx >> 19);
    const float v = X[idx];
    const unsigned short h1 = f2bf(v);
    const float r1 = v - bf2f(h1);
    const unsigned short h2 = f2bf(r1);
    const float r2 = r1 - bf2f(h2);
    const unsigned short h3 = f2bf(r2);
    const size_t fo = (((((size_t)tb * 64 + (n >> 4)) * 16 + (c >> 5)) * 64 +
                        ((n & 15) | (((c >> 3) & 3) << 4))) * 8) + (c & 7);
    xfr[fo]             = h1;
    xfr[TBCN + fo]      = h2;
    xfr[2 * TBCN + fo]  = h3;
}

// ---------------------------------------------------------------------------
// MFMA GEMM: Y[tb,o,n] = sum_c W[o,c]*X[tb,c,n] (+bias), via bf16 splits.
// NSB=3: products a1b1+a1b2+a2b1+a2b2+a1b3+a3b1 (err ~2^-23 |ab|).
// NSB=1: B exact in bf16 (binary spikes): a1b+a2b+a3b.
// No LDS, no barriers: operands pre-formatted, fragment loads are
// fully-coalesced 16B/lane from L2/L3. C/D map: col=lane&15, row=(lane>>4)*4+r.
// Block = 128(o) x 128(n), 4 waves, each wave 64x64 = 4x4 16x16 frags.
// ---------------------------------------------------------------------------
template <int NSB>
__global__ __launch_bounds__(256, 2) void mfma_gemm(
    const unsigned short* __restrict__ Afr,   // [3][32][16][64][8]
    const unsigned short* __restrict__ Bfr,   // [NSB][TBCN frag order]
    float* __restrict__ Y,                    // [tb][512][1024]
    const float* __restrict__ bias)
{
    const int tb   = blockIdx.z;
    const int lane = threadIdx.x & 63;
    const int wv   = threadIdx.x >> 6;
    const int wo = wv >> 1, wn = wv & 1;
    const int ob_base = blockIdx.y * 8 + wo * 4;   // 16-row units
    const int nb_base = blockIdx.x * 8 + wn * 4;   // 16-col units

    f32x4 acc[4][4];
    #pragma unroll
    for (int m = 0; m < 4; ++m)
        #pragma unroll
        for (int n = 0; n < 4; ++n)
            acc[m][n] = (f32x4){0.f, 0.f, 0.f, 0.f};

    for (int kb = 0; kb < 16; ++kb) {
        bf16x8 bf[4][NSB];
        #pragma unroll
        for (int n = 0; n < 4; ++n) {
            const size_t bo = ((((size_t)tb * 64 + (nb_base + n)) * 16 + kb) * 64 + lane) * 8;
            #pragma unroll
            for (int s = 0; s < NSB; ++s)
                bf[n][s] = *(const bf16x8*)(Bfr + (size_t)s * TBCN + bo);
        }
        #pragma unroll
        for (int m = 0; m < 4; ++m) {
            const size_t ao = ((((size_t)(ob_base + m)) * 16 + kb) * 64 + lane) * 8;
            const bf16x8 a1 = *(const bf16x8*)(Afr + ao);
            const bf16x8 a2 = *(const bf16x8*)(Afr + WFRS + ao);
            const bf16x8 a3 = *(const bf16x8*)(Afr + 2 * WFRS + ao);
            #pragma unroll
            for (int n = 0; n < 4; ++n) {
                if (NSB == 3) {
                    // small terms first
                    acc[m][n] = __builtin_amdgcn_mfma_f32_16x16x32_bf16(a3, bf[n][0], acc[m][n], 0, 0, 0);
                    acc[m][n] = __builtin_amdgcn_mfma_f32_16x16x32_bf16(a1, bf[n][2], acc[m][n], 0, 0, 0);
                    acc[m][n] = __builtin_amdgcn_mfma_f32_16x16x32_bf16(a2, bf[n][1], acc[m][n], 0, 0, 0);
                    acc[m][n] = __builtin_amdgcn_mfma_f32_16x16x32_bf16(a2, bf[n][0], acc[m][n], 0, 0, 0);
                    acc[m][n] = __builtin_amdgcn_mfma_f32_16x16x32_bf16(a1, bf[n][1], acc[m][n], 0, 0, 0);
                    acc[m][n] = __builtin_amdgcn_mfma_f32_16x16x32_bf16(a1, bf[n][0], acc[m][n], 0, 0, 0);
                } else {
                    acc[m][n] = __builtin_amdgcn_mfma_f32_16x16x32_bf16(a3, bf[n][0], acc[m][n], 0, 0, 0);
                    acc[m][n] = __builtin_amdgcn_mfma_f32_16x16x32_bf16(a2, bf[n][0], acc[m][n], 0, 0, 0);
                    acc[m][n] = __builtin_amdgcn_mfma_f32_16x16x32_bf16(a1, bf[n][0], acc[m][n], 0, 0, 0);
                }
            }
        }
    }

    float* Yb = Y + (size_t)tb * CDIM * NDIM;
    #pragma unroll
    for (int m = 0; m < 4; ++m) {
        const int row0 = (ob_base + m) * 16 + (lane >> 4) * 4;
        #pragma unroll
        for (int r = 0; r < 4; ++r) {
            const int row = row0 + r;
            const float bvv = bias ? bias[row] : 0.0f;
            #pragma unroll
            for (int n = 0; n < 4; ++n) {
                const int col = (nb_base + n) * 16 + (lane & 15);
                Yb[(size_t)row * NDIM + col] = acc[m][n][r] + bvv;
            }
        }
    }
}

// ---------------------------------------------------------------------------
// BN (optional) + LIF over T. One thread per (b,c,n).
// OUT_MODE 0: u8 spikes (optional) + optional ballot bitpack
// OUT_MODE 1: f32 spikes
// OUT_MODE 2: bf16 spikes written in B-fragment order (for projection GEMM)
// ---------------------------------------------------------------------------
template <int OUT_MODE>
__global__ __launch_bounds__(256) void lif_bn(
    const float* __restrict__ Y,
    const float* __restrict__ g, const float* __restrict__ b,
    const float* __restrict__ m, const float* __restrict__ var,
    float vth,
    unsigned char* __restrict__ s8, float* __restrict__ sf,
    unsigned short* __restrict__ sfr,
    u64* __restrict__ bits)
{
    const int idx = blockIdx.x * 256 + threadIdx.x;   // over B*C*N
    const int c = (idx >> 10) & (CDIM - 1);
    float inv = 1.0f, beta = 0.0f;
    if (g) {
        const float iv = g[c] / sqrtf(var[c] + 1e-5f);
        inv = iv;
        beta = __fsub_rn(b[c], __fmul_rn(m[c], iv));
    }
    float v = 0.0f;
    #pragma unroll
    for (int t = 0; t < TDIM; ++t) {
        float x = Y[(size_t)t * BCN + idx];
        x = __fadd_rn(__fmul_rn(x, inv), beta);
        v = __fadd_rn(v, __fmul_rn(__fsub_rn(x, v), 0.5f));
        const float s = (v >= vth) ? 1.0f : 0.0f;
        v = v * (1.0f - s);
        if (OUT_MODE == 0) {
            if (s8) s8[(size_t)t * BCN + idx] = (unsigned char)s;
        } else if (OUT_MODE == 1) {
            sf[(size_t)t * BCN + idx] = s;
        } else {
            const int n = idx & 1023;
            const int bb = idx >> 19;
            const int tb = t * BDIM + bb;
            const size_t fo = (((((size_t)tb * 64 + (n >> 4)) * 16 + (c >> 5)) * 64 +
                                ((n & 15) | (((c >> 3) & 3) << 4))) * 8) + (c & 7);
            sfr[fo] = s != 0.0f ? (unsigned short)0x3F80 : (unsigned short)0;
        }
        if (bits) {
            u64 mask = __ballot(s != 0.0f);
            if ((threadIdx.x & 63) == 0)
                bits[((size_t)t * BCN + idx) >> 6] = mask;
        }
    }
}

// ---------------------------------------------------------------------------
// v-branch spikes -> heads layout: out[t,b,h,n,dd] = sv[t,b,h*64+dd,n] (f32)
// ---------------------------------------------------------------------------
__global__ __launch_bounds__(256) void v_transpose(
    const unsigned char* __restrict__ sv, float* __restrict__ out)
{
    const int tbh = blockIdx.y;
    const int h = tbh & 7, tb = tbh >> 3;
    const int n0 = blockIdx.x * 64;
    __shared__ unsigned char tile[64][65];
    const int tid = threadIdx.x;
    const int lane = tid & 63;
    for (int dd = tid >> 6; dd < 64; dd += 4)
        tile[dd][lane] = sv[((size_t)tb * CDIM + h * 64 + dd) * NDIM + n0 + lane];
    __syncthreads();
    for (int nn = tid >> 6; nn < 64; nn += 4)
        out[((size_t)tbh * NDIM + n0 + nn) * 64 + lane] = (float)tile[lane][nn];
}

// ---------------------------------------------------------------------------
// kv[tbh,dd,e] = sum_n k[dd,n]*v[e,n] via popcount(AND) on bitpacked spikes.
// ---------------------------------------------------------------------------
__global__ __launch_bounds__(256) void kv_gemm(
    const u64* __restrict__ kb, const u64* __restrict__ vb,
    float* __restrict__ kv)
{
    const int tbh = blockIdx.x;
    const int h = tbh & 7, tb = tbh >> 3;
    __shared__ u64 sk[64][16], svv[64][16];
    const int tid = threadIdx.x;
    for (int i = tid; i < 1024; i += 256) {
        const int dd = i >> 4, w = i & 15;
        const size_t row = ((size_t)tb * CDIM + h * 64 + dd) * 16 + w;
        sk[dd][w] = kb[row];
        svv[dd][w] = vb[row];
    }
    __syncthreads();
    const int dd = tid >> 2, e0 = (tid & 3) * 16;
    #pragma unroll
    for (int j = 0; j < 16; ++j) {
        int acc = 0;
        #pragma unroll
        for (int w = 0; w < 16; ++w)
            acc += __popcll(sk[dd][w] & svv[e0 + j][w]);
        kv[((size_t)tbh * 64 + dd) * 64 + e0 + j] = (float)acc;
    }
}

// ---------------------------------------------------------------------------
// a[t,b,h*64+e,n] = 0.125 * sum_dd sq[t,b,h*64+dd,n] * kv[tbh,dd,e]
// ---------------------------------------------------------------------------
__global__ __launch_bounds__(256) void a_gemm(
    const float* __restrict__ kv, const unsigned char* __restrict__ sq,
    float* __restrict__ Y)
{
    const int tbh = blockIdx.y;
    const int h = tbh & 7, tb = tbh >> 3;
    const int n0 = blockIdx.x * 64;
    __shared__ float skv[64][65];
    __shared__ float sqt[64][64];
    const int tid = threadIdx.x;
    for (int i = tid; i < 4096; i += 256)
        skv[i >> 6][i & 63] = kv[(size_t)tbh * 4096 + i];
    const int lane = tid & 63;
    for (int dd = tid >> 6; dd < 64; dd += 4)
        sqt[dd][lane] = (float)sq[((size_t)tb * CDIM + h * 64 + dd) * NDIM + n0 + lane];
    __syncthreads();

    const int tx = tid & 15, ty = tid >> 4;
    float acc[4][4] = {};
    #pragma unroll 8
    for (int dd = 0; dd < 64; ++dd) {
        float a_[4];
        #pragma unroll
        for (int i = 0; i < 4; ++i) a_[i] = skv[dd][ty * 4 + i];
        float4 b4 = *(float4*)&sqt[dd][tx * 4];
        float b_[4] = {b4.x, b4.y, b4.z, b4.w};
        #pragma unroll
        for (int i = 0; i < 4; ++i)
            #pragma unroll
            for (int j = 0; j < 4; ++j)
                acc[i][j] += a_[i] * b_[j];
    }
    #pragma unroll
    for (int i = 0; i < 4; ++i) {
        const int e = ty * 4 + i;
        float4 r = make_float4(acc[i][0] * 0.125f, acc[i][1] * 0.125f,
                               acc[i][2] * 0.125f, acc[i][3] * 0.125f);
        *(float4*)(Y + ((size_t)tb * CDIM + h * 64 + e) * NDIM + n0 + tx * 4) = r;
    }
}

// ---------------------------------------------------------------------------
extern "C" void kernel_launch(void* const* d_in, const int* in_sizes, int n_in,
                              void* d_out, int out_size, void* d_ws, size_t ws_size,
                              hipStream_t stream)
{
    const float* x  = (const float*)d_in[0];
    const float* wq = (const float*)d_in[2];
    const float* gq = (const float*)d_in[3];
    const float* bq = (const float*)d_in[4];
    const float* mq = (const float*)d_in[5];
    const float* vq = (const float*)d_in[6];
    const float* wk = (const float*)d_in[7];
    const float* gk = (const float*)d_in[8];
    const float* bk = (const float*)d_in[9];
    const float* mk = (const float*)d_in[10];
    const float* vk = (const float*)d_in[11];
    const float* wv = (const float*)d_in[12];
    const float* gv = (const float*)d_in[13];
    const float* bv = (const float*)d_in[14];
    const float* mv = (const float*)d_in[15];
    const float* vv = (const float*)d_in[16];
    const float* wp = (const float*)d_in[17];
    const float* pb = (const float*)d_in[18];
    const float* gp = (const float*)d_in[19];
    const float* bp = (const float*)d_in[20];
    const float* mp = (const float*)d_in[21];
    const float* vp = (const float*)d_in[22];
    (void)in_sizes; (void)n_in; (void)out_size; (void)ws_size;

    // workspace carve (~216 MB)
    char* w = (char*)d_ws;
    float* Y = (float*)w;                     w += TBCN * 4;            // 67 MB
    unsigned short* xfr = (unsigned short*)w; w += 3 * TBCN * 2;        // 100.6 MB
    unsigned short* wfr = (unsigned short*)w; w += (size_t)4 * 3 * WFRS * 2; // 6.3 MB
    unsigned char* sq = (unsigned char*)w;    w += TBCN;                // 16.7 MB
    unsigned char* sv = (unsigned char*)w;    w += TBCN;                // 16.7 MB
    u64* kbb = (u64*)w;                       w += TBCN / 8;            // 2 MB
    u64* vbb = (u64*)w;                       w += TBCN / 8;            // 2 MB
    float* kvbuf = (float*)w;                 w += (size_t)256 * 4096 * 4; // 4 MB
    unsigned short* safr = xfr;   // alias: x_fr dead after v-branch GEMM

    float* out_spk = (float*)d_out;           // (T,B,C,N)
    float* out_v   = (float*)d_out + TBCN;    // (T,B,H,N,d)

    const dim3 blk(256);
    const dim3 gemmGrid(NDIM / 128, CDIM / 128, TDIM * BDIM);  // 8,4,32 = 1024
    const int lifGrid = BCN / 256;

    // operand formatting
    wsplit<<<WFRS / 256, blk, 0, stream>>>(wq, wfr + (size_t)0 * 3 * WFRS);
    wsplit<<<WFRS / 256, blk, 0, stream>>>(wk, wfr + (size_t)1 * 3 * WFRS);
    wsplit<<<WFRS / 256, blk, 0, stream>>>(wv, wfr + (size_t)2 * 3 * WFRS);
    wsplit<<<WFRS / 256, blk, 0, stream>>>(wp, wfr + (size_t)3 * 3 * WFRS);
    xsplit<<<(int)(TBCN / 256), blk, 0, stream>>>(x, xfr);

    // q branch
    mfma_gemm<3><<<gemmGrid, blk, 0, stream>>>(wfr + (size_t)0 * 3 * WFRS, xfr, Y, nullptr);
    lif_bn<0><<<lifGrid, blk, 0, stream>>>(Y, gq, bq, mq, vq, 1.0f, sq, nullptr, nullptr, nullptr);
    // k branch (bits only)
    mfma_gemm<3><<<gemmGrid, blk, 0, stream>>>(wfr + (size_t)1 * 3 * WFRS, xfr, Y, nullptr);
    lif_bn<0><<<lifGrid, blk, 0, stream>>>(Y, gk, bk, mk, vk, 1.0f, nullptr, nullptr, nullptr, kbb);
    // v branch (u8 + bits)
    mfma_gemm<3><<<gemmGrid, blk, 0, stream>>>(wfr + (size_t)2 * 3 * WFRS, xfr, Y, nullptr);
    lif_bn<0><<<lifGrid, blk, 0, stream>>>(Y, gv, bv, mv, vv, 1.0f, sv, nullptr, nullptr, vbb);
    // v spikes -> heads output
    v_transpose<<<dim3(NDIM / 64, TDIM * BDIM * HDIM), blk, 0, stream>>>(sv, out_v);
    // attention (exact integer arithmetic)
    kv_gemm<<<TDIM * BDIM * HDIM, blk, 0, stream>>>(kbb, vbb, kvbuf);
    a_gemm<<<dim3(NDIM / 64, TDIM * BDIM * HDIM), blk, 0, stream>>>(kvbuf, sq, Y);
    // attn LIF -> bf16 spikes in fragment order
    lif_bn<2><<<lifGrid, blk, 0, stream>>>(Y, nullptr, nullptr, nullptr, nullptr, 0.5f,
                                           nullptr, nullptr, safr, nullptr);
    // projection (spike input exact in bf16: 3 passes) + bias, then BN+LIF -> out
    mfma_gemm<1><<<gemmGrid, blk, 0, stream>>>(wfr + (size_t)3 * 3 * WFRS, safr, Y, pb);
    lif_bn<1><<<lifGrid, blk, 0, stream>>>(Y, gp, bp, mp, vp, 1.0f, nullptr, out_spk, nullptr, nullptr);
}